// Round 1
// baseline (1697.700 us; speedup 1.0000x reference)
//
#include <hip/hip_runtime.h>
#include <hip/hip_bf16.h>
#include <math.h>

typedef unsigned int u32;
typedef unsigned short u16;

#define EPSF 1e-8f

__device__ __forceinline__ float bf2f(u16 h) {
    union { u32 u; float f; } v; v.u = ((u32)h) << 16; return v.f;
}
__device__ __forceinline__ u16 f2bf(float f) {
    union { float ff; u32 u; } v; v.ff = f;
    u32 u = v.u;
    return (u16)((u + 0x7fffu + ((u >> 16) & 1u)) >> 16);
}
__device__ __forceinline__ float gelu_exact(float v) {
    return 0.5f * v * (1.0f + erff(v * 0.70710678118654752440f));
}

// ---------------- K1: depthwise conv + pointwise + channel-RMSNorm + GELU ----------------
// block = 256 threads, tile = 32 L-positions. x column (38 rows) loaded coalesced
// straight into registers (lane = channel). hsh: conv result tile in LDS for the
// pointwise GEMM (broadcast float4 reads). fs overlays hsh for the RMS reduction.
template<int S>
__device__ __forceinline__ void process_scale(
    const float* __restrict__ dw, const float* __restrict__ pw, const float* __restrict__ cn,
    const float* xc, float* hsh, float* rinv,
    int t, size_t row0, u32* __restrict__ feats32)
{
    const int K = 2 * S + 1;
    const int c = t;
    // depthwise conv (cross-correlation, zero-padded) from registers
    float d[K];
    #pragma unroll
    for (int j = 0; j < K; j++) d[j] = dw[c * K + j];
    #pragma unroll
    for (int l = 0; l < 32; l++) {
        float a = 0.f;
        #pragma unroll
        for (int j = 0; j < K; j++) a += xc[l + 3 - S + j] * d[j];
        hsh[l * 256 + c] = a;
    }
    __syncthreads();
    // pointwise GEMM: thread -> 2 output channels x 8 positions
    const int oh = t & 63;
    const int o0 = oh * 2;
    const int lg = t >> 6;
    const float* pr0 = pw + (size_t)o0 * 256;
    const float* pr1 = pr0 + 256;
    float acc0[8], acc1[8];
    #pragma unroll
    for (int i = 0; i < 8; i++) { acc0[i] = 0.f; acc1[i] = 0.f; }
    for (int c4 = 0; c4 < 256; c4 += 4) {
        float4 w0 = *(const float4*)(pr0 + c4);
        float4 w1 = *(const float4*)(pr1 + c4);
        #pragma unroll
        for (int i = 0; i < 8; i++) {
            const float4 h = *(const float4*)&hsh[(lg * 8 + i) * 256 + c4];
            acc0[i] += h.x * w0.x + h.y * w0.y + h.z * w0.z + h.w * w0.w;
            acc1[i] += h.x * w1.x + h.y * w1.y + h.z * w1.z + h.w * w1.w;
        }
    }
    __syncthreads();
    // RMS over the 128 channels per position: stage values in fs (overlay on hsh)
    float* fs = hsh;
    #pragma unroll
    for (int i = 0; i < 8; i++) {
        fs[(lg * 8 + i) * 132 + o0]     = acc0[i];
        fs[(lg * 8 + i) * 132 + o0 + 1] = acc1[i];
    }
    __syncthreads();
    {
        int lr = t >> 3, part = t & 7;
        float ss = 0.f;
        #pragma unroll
        for (int j = 0; j < 16; j++) { float v = fs[lr * 132 + part * 16 + j]; ss += v * v; }
        ss += __shfl_xor(ss, 1);
        ss += __shfl_xor(ss, 2);
        ss += __shfl_xor(ss, 4);
        if (part == 0) rinv[lr] = 1.0f / (sqrtf(ss * (1.0f / 128.0f)) + EPSF);
    }
    __syncthreads();
    {
        float cn0 = cn[o0], cn1 = cn[o0 + 1];
        #pragma unroll
        for (int i = 0; i < 8; i++) {
            int l = lg * 8 + i;
            float r = rinv[l];
            float g0 = gelu_exact(acc0[i] * r * cn0);
            float g1 = gelu_exact(acc1[i] * r * cn1);
            u32 pk = (u32)f2bf(g0) | ((u32)f2bf(g1) << 16);
            feats32[(row0 + (size_t)l) * 256 + S * 64 + oh] = pk;
        }
    }
    __syncthreads();
}

__global__ __launch_bounds__(256) void k_feats(
    const float* __restrict__ x,
    const float* __restrict__ dw1, const float* __restrict__ pw1, const float* __restrict__ cn1,
    const float* __restrict__ dw3, const float* __restrict__ pw3, const float* __restrict__ cn3,
    const float* __restrict__ dw5, const float* __restrict__ pw5, const float* __restrict__ cn5,
    const float* __restrict__ dw7, const float* __restrict__ pw7, const float* __restrict__ cn7,
    u32* __restrict__ feats32)
{
    __shared__ float hsh[32 * 256];
    __shared__ float rinv[32];
    const int t = threadIdx.x;
    const int l0 = blockIdx.x * 32;
    const int b = blockIdx.y;
    const float* xb = x + (size_t)b * 4096 * 256;
    float xc[38];
    #pragma unroll
    for (int r = 0; r < 38; r++) {
        int g = l0 - 3 + r;
        xc[r] = (g >= 0 && g < 4096) ? xb[(size_t)g * 256 + t] : 0.0f;
    }
    size_t row0 = (size_t)b * 4096 + l0;
    process_scale<0>(dw1, pw1, cn1, xc, hsh, rinv, t, row0, feats32);
    process_scale<1>(dw3, pw3, cn3, xc, hsh, rinv, t, row0, feats32);
    process_scale<2>(dw5, pw5, cn5, xc, hsh, rinv, t, row0, feats32);
    process_scale<3>(dw7, pw7, cn7, xc, hsh, rinv, t, row0, feats32);
}

// ---------------- K2: attention MLP + softmax over 4 scales ----------------
__global__ __launch_bounds__(256) void k_attn(
    const u16* __restrict__ feats,
    const float* __restrict__ w1, const float* __restrict__ b1,
    const float* __restrict__ w2, const float* __restrict__ b2,
    float* __restrict__ attnw)
{
    __shared__ float fsh[16 * 512];
    __shared__ float as1[16 * 132];
    const int t = threadIdx.x;
    const size_t n0 = (size_t)blockIdx.x * 16;
    const uint4* src = (const uint4*)(feats + n0 * 512);
    #pragma unroll
    for (int i = 0; i < 4; i++) {
        uint4 v = src[i * 256 + t];
        float* dst = &fsh[(i * 256 + t) * 8];
        dst[0] = bf2f((u16)(v.x & 0xffffu)); dst[1] = bf2f((u16)(v.x >> 16));
        dst[2] = bf2f((u16)(v.y & 0xffffu)); dst[3] = bf2f((u16)(v.y >> 16));
        dst[4] = bf2f((u16)(v.z & 0xffffu)); dst[5] = bf2f((u16)(v.z >> 16));
        dst[6] = bf2f((u16)(v.w & 0xffffu)); dst[7] = bf2f((u16)(v.w >> 16));
    }
    __syncthreads();
    {
        const int o = t & 127, half = t >> 7;
        const float* w1r = w1 + (size_t)o * 512;
        float acc[8];
        #pragma unroll
        for (int i = 0; i < 8; i++) acc[i] = 0.f;
        for (int c4 = 0; c4 < 512; c4 += 4) {
            float4 w = *(const float4*)(w1r + c4);
            #pragma unroll
            for (int i = 0; i < 8; i++) {
                const float4 f = *(const float4*)&fsh[(half * 8 + i) * 512 + c4];
                acc[i] += f.x * w.x + f.y * w.y + f.z * w.z + f.w * w.w;
            }
        }
        float bb = b1[o];
        #pragma unroll
        for (int i = 0; i < 8; i++)
            as1[(half * 8 + i) * 132 + o] = gelu_exact(acc[i] + bb);
    }
    __syncthreads();
    {
        const int p = t >> 4, part = t & 15;
        float a2[4] = {0.f, 0.f, 0.f, 0.f};
        #pragma unroll
        for (int j = 0; j < 8; j++) {
            int o = part * 8 + j;
            float av = as1[p * 132 + o];
            #pragma unroll
            for (int s = 0; s < 4; s++) a2[s] += av * w2[s * 128 + o];
        }
        #pragma unroll
        for (int m = 1; m < 16; m <<= 1) {
            #pragma unroll
            for (int s = 0; s < 4; s++) a2[s] += __shfl_xor(a2[s], m);
        }
        if (part == 0) {
            float v0 = a2[0] + b2[0], v1 = a2[1] + b2[1], v2 = a2[2] + b2[2], v3 = a2[3] + b2[3];
            float mx = fmaxf(fmaxf(v0, v1), fmaxf(v2, v3));
            float e0 = expf(v0 - mx), e1 = expf(v1 - mx), e2 = expf(v2 - mx), e3 = expf(v3 - mx);
            float inv = 1.0f / (e0 + e1 + e2 + e3);
            *(float4*)&attnw[(n0 + p) * 4] = make_float4(e0 * inv, e1 * inv, e2 * inv, e3 * inv);
        }
    }
}

// ---------------- K3: final conv + residual GEMM (K = 512 feats*attn  ||  256 x) ----------------
// 64x64 output tile per block, K-tiles of 32, pre-norm result to d_out.
__global__ __launch_bounds__(256) void k_final(
    const u16* __restrict__ feats, const float* __restrict__ attnw,
    const float* __restrict__ x,
    const float* __restrict__ fw, const float* __restrict__ rw,
    float* __restrict__ out)
{
    __shared__ float As[32 * 68];
    __shared__ float Ws[32 * 68];
    const int t = threadIdx.x;
    const int n0 = blockIdx.x * 64;
    const size_t m0 = (size_t)blockIdx.y * 64;
    const int tx = t & 15, ty = t >> 4;
    const int mloc = t >> 3;
    const int kc = (t & 7) * 4;
    float acc[4][4];
    #pragma unroll
    for (int i = 0; i < 4; i++)
        #pragma unroll
        for (int j = 0; j < 4; j++) acc[i][j] = 0.f;

    for (int kt = 0; kt < 24; kt++) {
        const int kg = kt * 32;
        #pragma unroll
        for (int h = 0; h < 2; h++) {
            const int m = mloc + h * 32;
            float f0, f1, f2, f3;
            if (kt < 16) {
                const u16* fp = feats + (m0 + m) * 512 + kg + kc;
                uint2 raw = *(const uint2*)fp;
                float aw = attnw[(m0 + m) * 4 + (kg >> 7)];
                f0 = bf2f((u16)(raw.x & 0xffffu)) * aw;
                f1 = bf2f((u16)(raw.x >> 16)) * aw;
                f2 = bf2f((u16)(raw.y & 0xffffu)) * aw;
                f3 = bf2f((u16)(raw.y >> 16)) * aw;
            } else {
                const float4 xv = *(const float4*)(x + (m0 + m) * 256 + (size_t)(kg - 512) + kc);
                f0 = xv.x; f1 = xv.y; f2 = xv.z; f3 = xv.w;
            }
            As[(kc + 0) * 68 + m] = f0;
            As[(kc + 1) * 68 + m] = f1;
            As[(kc + 2) * 68 + m] = f2;
            As[(kc + 3) * 68 + m] = f3;
            float4 wv;
            if (kt < 16) wv = *(const float4*)(fw + (size_t)(n0 + m) * 512 + kg + kc);
            else         wv = *(const float4*)(rw + (size_t)(n0 + m) * 256 + (kg - 512) + kc);
            Ws[(kc + 0) * 68 + m] = wv.x;
            Ws[(kc + 1) * 68 + m] = wv.y;
            Ws[(kc + 2) * 68 + m] = wv.z;
            Ws[(kc + 3) * 68 + m] = wv.w;
        }
        __syncthreads();
        #pragma unroll
        for (int k = 0; k < 32; k++) {
            const float4 a = *(const float4*)&As[k * 68 + ty * 4];
            const float4 w = *(const float4*)&Ws[k * 68 + tx * 4];
            acc[0][0] += a.x * w.x; acc[0][1] += a.x * w.y; acc[0][2] += a.x * w.z; acc[0][3] += a.x * w.w;
            acc[1][0] += a.y * w.x; acc[1][1] += a.y * w.y; acc[1][2] += a.y * w.z; acc[1][3] += a.y * w.w;
            acc[2][0] += a.z * w.x; acc[2][1] += a.z * w.y; acc[2][2] += a.z * w.z; acc[2][3] += a.z * w.w;
            acc[3][0] += a.w * w.x; acc[3][1] += a.w * w.y; acc[3][2] += a.w * w.z; acc[3][3] += a.w * w.w;
        }
        __syncthreads();
    }
    #pragma unroll
    for (int i = 0; i < 4; i++) {
        *(float4*)&out[(m0 + ty * 4 + i) * 512 + n0 + tx * 4] =
            make_float4(acc[i][0], acc[i][1], acc[i][2], acc[i][3]);
    }
}

// ---------------- K4: in-place row RMSNorm over 512 ----------------
__global__ __launch_bounds__(256) void k_norm(
    float* __restrict__ out, const float* __restrict__ nsc)
{
    __shared__ float part[2][2];
    const int t = threadIdx.x;
    const int r = t >> 7;
    const int cc = (t & 127) * 4;
    const size_t row = (size_t)blockIdx.x * 2 + r;
    float4 v = *(float4*)&out[row * 512 + cc];
    float ss = v.x * v.x + v.y * v.y + v.z * v.z + v.w * v.w;
    #pragma unroll
    for (int m = 1; m < 64; m <<= 1) ss += __shfl_xor(ss, m);
    if ((t & 63) == 0) part[r][(t >> 6) & 1] = ss;
    __syncthreads();
    float tot = part[r][0] + part[r][1];
    float rv = 1.0f / (sqrtf(tot * (1.0f / 512.0f)) + EPSF);
    const float4 s4 = *(const float4*)&nsc[cc];
    v.x *= rv * s4.x; v.y *= rv * s4.y; v.z *= rv * s4.z; v.w *= rv * s4.w;
    *(float4*)&out[row * 512 + cc] = v;
}

extern "C" void kernel_launch(void* const* d_in, const int* in_sizes, int n_in,
                              void* d_out, int out_size, void* d_ws, size_t ws_size,
                              hipStream_t stream)
{
    const float* x   = (const float*)d_in[0];
    const float* dw1 = (const float*)d_in[1];
    const float* pw1 = (const float*)d_in[2];
    const float* cn1 = (const float*)d_in[3];
    const float* dw3 = (const float*)d_in[4];
    const float* pw3 = (const float*)d_in[5];
    const float* cn3 = (const float*)d_in[6];
    const float* dw5 = (const float*)d_in[7];
    const float* pw5 = (const float*)d_in[8];
    const float* cn5 = (const float*)d_in[9];
    const float* dw7 = (const float*)d_in[10];
    const float* pw7 = (const float*)d_in[11];
    const float* cn7 = (const float*)d_in[12];
    const float* w1  = (const float*)d_in[13];
    const float* b1  = (const float*)d_in[14];
    const float* w2  = (const float*)d_in[15];
    const float* b2  = (const float*)d_in[16];
    const float* fw  = (const float*)d_in[17];
    const float* nsc = (const float*)d_in[18];
    const float* rw  = (const float*)d_in[19];

    // workspace: feats bf16 [65536][512] (64 MB) + attn fp32 [65536][4] (1 MB)
    u16* feats   = (u16*)d_ws;
    float* attnw = (float*)((char*)d_ws + (size_t)67108864);
    float* out   = (float*)d_out;
    if (ws_size < (size_t)68157440) return;  // not enough scratch -> leave poison (loud failure)

    k_feats<<<dim3(128, 16), 256, 0, stream>>>(x, dw1, pw1, cn1, dw3, pw3, cn3,
                                               dw5, pw5, cn5, dw7, pw7, cn7, (u32*)feats);
    k_attn<<<dim3(4096), 256, 0, stream>>>(feats, w1, b1, w2, b2, attnw);
    k_final<<<dim3(8, 1024), 256, 0, stream>>>(feats, attnw, x, fw, rw, out);
    k_norm<<<dim3(32768), 256, 0, stream>>>(out, nsc);
}

// Round 2
// 1111.629 us; speedup vs baseline: 1.5272x; 1.5272x over previous
//
#include <hip/hip_runtime.h>
#include <hip/hip_bf16.h>
#include <math.h>

typedef unsigned int u32;
typedef unsigned short u16;

typedef __bf16 bf16_t;
typedef bf16_t bf16x8 __attribute__((ext_vector_type(8)));
typedef float f32x4 __attribute__((ext_vector_type(4)));

#define EPSF 1e-8f

__device__ __forceinline__ float bf2f(u16 h) {
    union { u32 u; float f; } v; v.u = ((u32)h) << 16; return v.f;
}
__device__ __forceinline__ u16 f2bf(float f) {
    union { float ff; u32 u; } v; v.ff = f;
    u32 u = v.u;
    return (u16)((u + 0x7fffu + ((u >> 16) & 1u)) >> 16);
}
__device__ __forceinline__ float gelu_exact(float v) {
    return 0.5f * v * (1.0f + erff(v * 0.70710678118654752440f));
}
__device__ __forceinline__ void gld_lds16(const void* g, void* l) {
    __builtin_amdgcn_global_load_lds(
        (const __attribute__((address_space(1))) unsigned int*)g,
        (__attribute__((address_space(3))) unsigned int*)l, 16, 0, 0);
}

// ---------------- K1: depthwise conv + pointwise + channel-RMSNorm + GELU ----------------
template<int S>
__device__ __forceinline__ void process_scale(
    const float* __restrict__ dw, const float* __restrict__ pw, const float* __restrict__ cn,
    const float* xc, float* hsh, float* rinv,
    int t, size_t row0, u32* __restrict__ feats32)
{
    const int K = 2 * S + 1;
    const int c = t;
    float d[K];
    #pragma unroll
    for (int j = 0; j < K; j++) d[j] = dw[c * K + j];
    #pragma unroll
    for (int l = 0; l < 32; l++) {
        float a = 0.f;
        #pragma unroll
        for (int j = 0; j < K; j++) a += xc[l + 3 - S + j] * d[j];
        hsh[l * 256 + c] = a;
    }
    __syncthreads();
    const int oh = t & 63;
    const int o0 = oh * 2;
    const int lg = t >> 6;
    const float* pr0 = pw + (size_t)o0 * 256;
    const float* pr1 = pr0 + 256;
    float acc0[8], acc1[8];
    #pragma unroll
    for (int i = 0; i < 8; i++) { acc0[i] = 0.f; acc1[i] = 0.f; }
    for (int c4 = 0; c4 < 256; c4 += 4) {
        float4 w0 = *(const float4*)(pr0 + c4);
        float4 w1 = *(const float4*)(pr1 + c4);
        #pragma unroll
        for (int i = 0; i < 8; i++) {
            const float4 h = *(const float4*)&hsh[(lg * 8 + i) * 256 + c4];
            acc0[i] += h.x * w0.x + h.y * w0.y + h.z * w0.z + h.w * w0.w;
            acc1[i] += h.x * w1.x + h.y * w1.y + h.z * w1.z + h.w * w1.w;
        }
    }
    __syncthreads();
    float* fs = hsh;
    #pragma unroll
    for (int i = 0; i < 8; i++) {
        fs[(lg * 8 + i) * 132 + o0]     = acc0[i];
        fs[(lg * 8 + i) * 132 + o0 + 1] = acc1[i];
    }
    __syncthreads();
    {
        int lr = t >> 3, part = t & 7;
        float ss = 0.f;
        #pragma unroll
        for (int j = 0; j < 16; j++) { float v = fs[lr * 132 + part * 16 + j]; ss += v * v; }
        ss += __shfl_xor(ss, 1);
        ss += __shfl_xor(ss, 2);
        ss += __shfl_xor(ss, 4);
        if (part == 0) rinv[lr] = 1.0f / (sqrtf(ss * (1.0f / 128.0f)) + EPSF);
    }
    __syncthreads();
    {
        float cn0 = cn[o0], cn1 = cn[o0 + 1];
        #pragma unroll
        for (int i = 0; i < 8; i++) {
            int l = lg * 8 + i;
            float r = rinv[l];
            float g0 = gelu_exact(acc0[i] * r * cn0);
            float g1 = gelu_exact(acc1[i] * r * cn1);
            u32 pk = (u32)f2bf(g0) | ((u32)f2bf(g1) << 16);
            feats32[(row0 + (size_t)l) * 256 + S * 64 + oh] = pk;
        }
    }
    __syncthreads();
}

__global__ __launch_bounds__(256) void k_feats(
    const float* __restrict__ x,
    const float* __restrict__ dw1, const float* __restrict__ pw1, const float* __restrict__ cn1,
    const float* __restrict__ dw3, const float* __restrict__ pw3, const float* __restrict__ cn3,
    const float* __restrict__ dw5, const float* __restrict__ pw5, const float* __restrict__ cn5,
    const float* __restrict__ dw7, const float* __restrict__ pw7, const float* __restrict__ cn7,
    u32* __restrict__ feats32)
{
    __shared__ float hsh[32 * 256];
    __shared__ float rinv[32];
    const int t = threadIdx.x;
    const int l0 = blockIdx.x * 32;
    const int b = blockIdx.y;
    const float* xb = x + (size_t)b * 4096 * 256;
    float xc[38];
    #pragma unroll
    for (int r = 0; r < 38; r++) {
        int g = l0 - 3 + r;
        xc[r] = (g >= 0 && g < 4096) ? xb[(size_t)g * 256 + t] : 0.0f;
    }
    size_t row0 = (size_t)b * 4096 + l0;
    process_scale<0>(dw1, pw1, cn1, xc, hsh, rinv, t, row0, feats32);
    process_scale<1>(dw3, pw3, cn3, xc, hsh, rinv, t, row0, feats32);
    process_scale<2>(dw5, pw5, cn5, xc, hsh, rinv, t, row0, feats32);
    process_scale<3>(dw7, pw7, cn7, xc, hsh, rinv, t, row0, feats32);
}

// ---------------- K2: attention MLP + softmax + IN-PLACE feats scaling ----------------
__global__ __launch_bounds__(256) void k_attn(
    u16* __restrict__ feats,
    const float* __restrict__ w1, const float* __restrict__ b1,
    const float* __restrict__ w2, const float* __restrict__ b2)
{
    __shared__ float fsh[16 * 512];
    __shared__ float as1[16 * 132];
    __shared__ float att4[16][4];
    const int t = threadIdx.x;
    const size_t n0 = (size_t)blockIdx.x * 16;
    uint4* base = (uint4*)(feats + n0 * 512);
    uint4 v[4];
    #pragma unroll
    for (int i = 0; i < 4; i++) {
        v[i] = base[i * 256 + t];
        float* dst = &fsh[(i * 256 + t) * 8];
        dst[0] = bf2f((u16)(v[i].x & 0xffffu)); dst[1] = bf2f((u16)(v[i].x >> 16));
        dst[2] = bf2f((u16)(v[i].y & 0xffffu)); dst[3] = bf2f((u16)(v[i].y >> 16));
        dst[4] = bf2f((u16)(v[i].z & 0xffffu)); dst[5] = bf2f((u16)(v[i].z >> 16));
        dst[6] = bf2f((u16)(v[i].w & 0xffffu)); dst[7] = bf2f((u16)(v[i].w >> 16));
    }
    __syncthreads();
    {
        const int o = t & 127, half = t >> 7;
        const float* w1r = w1 + (size_t)o * 512;
        float acc[8];
        #pragma unroll
        for (int i = 0; i < 8; i++) acc[i] = 0.f;
        for (int c4 = 0; c4 < 512; c4 += 4) {
            float4 w = *(const float4*)(w1r + c4);
            #pragma unroll
            for (int i = 0; i < 8; i++) {
                const float4 f = *(const float4*)&fsh[(half * 8 + i) * 512 + c4];
                acc[i] += f.x * w.x + f.y * w.y + f.z * w.z + f.w * w.w;
            }
        }
        float bb = b1[o];
        #pragma unroll
        for (int i = 0; i < 8; i++)
            as1[(half * 8 + i) * 132 + o] = gelu_exact(acc[i] + bb);
    }
    __syncthreads();
    {
        const int p = t >> 4, part = t & 15;
        float a2[4] = {0.f, 0.f, 0.f, 0.f};
        #pragma unroll
        for (int j = 0; j < 8; j++) {
            int o = part * 8 + j;
            float av = as1[p * 132 + o];
            #pragma unroll
            for (int s = 0; s < 4; s++) a2[s] += av * w2[s * 128 + o];
        }
        #pragma unroll
        for (int m = 1; m < 16; m <<= 1) {
            #pragma unroll
            for (int s = 0; s < 4; s++) a2[s] += __shfl_xor(a2[s], m);
        }
        if (part == 0) {
            float v0 = a2[0] + b2[0], v1 = a2[1] + b2[1], v2 = a2[2] + b2[2], v3 = a2[3] + b2[3];
            float mx = fmaxf(fmaxf(v0, v1), fmaxf(v2, v3));
            float e0 = expf(v0 - mx), e1 = expf(v1 - mx), e2 = expf(v2 - mx), e3 = expf(v3 - mx);
            float inv = 1.0f / (e0 + e1 + e2 + e3);
            att4[p][0] = e0 * inv; att4[p][1] = e1 * inv; att4[p][2] = e2 * inv; att4[p][3] = e3 * inv;
        }
    }
    __syncthreads();
    // in-place scale: feats[n, c] *= attn[n, c/128]
    #pragma unroll
    for (int i = 0; i < 4; i++) {
        int idx = i * 256 + t;
        int row = idx >> 6;          // local position 0..15
        int sc = (idx & 63) >> 4;    // scale block 0..3
        float a = att4[row][sc];
        uint4 w = v[i];
        u32 r0 = (u32)f2bf(bf2f((u16)(w.x & 0xffffu)) * a) | ((u32)f2bf(bf2f((u16)(w.x >> 16)) * a) << 16);
        u32 r1 = (u32)f2bf(bf2f((u16)(w.y & 0xffffu)) * a) | ((u32)f2bf(bf2f((u16)(w.y >> 16)) * a) << 16);
        u32 r2 = (u32)f2bf(bf2f((u16)(w.z & 0xffffu)) * a) | ((u32)f2bf(bf2f((u16)(w.z >> 16)) * a) << 16);
        u32 r3 = (u32)f2bf(bf2f((u16)(w.w & 0xffffu)) * a) | ((u32)f2bf(bf2f((u16)(w.w >> 16)) * a) << 16);
        base[idx] = make_uint4(r0, r1, r2, r3);
    }
}

// ---------------- K2b: pack final_w || res_w into bf16 [512][768] ----------------
__global__ __launch_bounds__(256) void k_packw(
    const float* __restrict__ fw, const float* __restrict__ rw, u16* __restrict__ wb)
{
    const int n = blockIdx.x;
    const int k = blockIdx.y * 256 + threadIdx.x;
    float v = (k < 512) ? fw[(size_t)n * 512 + k] : rw[(size_t)n * 256 + (k - 512)];
    wb[(size_t)n * 768 + k] = f2bf(v);
}

// ---------------- K3: MFMA GEMM — out[65536,512] = A[65536,768] * W[512,768]^T ----------------
// A = [scaled feats bf16 (k<512) | x cast to bf16 (k>=512)], W = [final_w | res_w] bf16.
// 128x128 tile, BK=32, 16x16x32 bf16 MFMA, global_load_lds width=16,
// XOR-swizzled 16B k-groups: g' = g ^ ((row>>1)&3) -> 2-way (free) LDS banking.
__global__ __launch_bounds__(256) void k_final_mfma(
    const u16* __restrict__ feats, const float* __restrict__ x,
    const u16* __restrict__ wb, float* __restrict__ out)
{
    __shared__ __align__(16) u16 As[128 * 32];
    __shared__ __align__(16) u16 Bs[128 * 32];
    const int t = threadIdx.x;
    const int lane = t & 63;
    const int wave = t >> 6;
    const int m0 = blockIdx.x * 128;
    const int n0 = blockIdx.y * 128;

    // async staging coords: wave covers rows [wave*32, wave*32+32), call j adds 16
    const int srow_b = wave * 32 + (lane >> 2);
    const int sgp = lane & 3;

    f32x4 acc[4][4];
    #pragma unroll
    for (int i = 0; i < 4; i++)
        #pragma unroll
        for (int j = 0; j < 4; j++) acc[i][j] = f32x4{0.f, 0.f, 0.f, 0.f};

    const int wm = (wave & 1) * 64;
    const int wn = (wave >> 1) * 64;
    int a_off[4], b_off[4];
    #pragma unroll
    for (int i = 0; i < 4; i++) {
        int ra = wm + i * 16 + (lane & 15);
        a_off[i] = ra * 32 + (((lane >> 4) ^ ((ra >> 1) & 3)) * 8);
        int rb = wn + i * 16 + (lane & 15);
        b_off[i] = rb * 32 + (((lane >> 4) ^ ((rb >> 1) & 3)) * 8);
    }

    for (int kt = 0; kt < 24; ++kt) {
        const int k0 = kt * 32;
        // W tile: always async bf16
        #pragma unroll
        for (int j = 0; j < 2; j++) {
            int r = srow_b + j * 16;
            int g = sgp ^ ((r >> 1) & 3);
            gld_lds16(wb + (size_t)(n0 + r) * 768 + k0 + g * 8,
                      &Bs[wave * 1024 + j * 512]);
        }
        if (kt < 16) {
            // A tile from scaled feats (bf16), async
            #pragma unroll
            for (int j = 0; j < 2; j++) {
                int r = srow_b + j * 16;
                int g = sgp ^ ((r >> 1) & 3);
                gld_lds16(feats + (size_t)(m0 + r) * 512 + k0 + g * 8,
                          &As[wave * 1024 + j * 512]);
            }
        } else {
            // A tile from x (fp32 -> bf16 in-kernel)
            const int kx0 = (kt - 16) * 32;
            const int row = t >> 1;
            #pragma unroll
            for (int h = 0; h < 2; h++) {
                int g2 = (t & 1) * 2 + h;
                const float4* xp = (const float4*)(x + (size_t)(m0 + row) * 256 + kx0 + g2 * 8);
                float4 v0 = xp[0], v1 = xp[1];
                u32 p0 = (u32)f2bf(v0.x) | ((u32)f2bf(v0.y) << 16);
                u32 p1 = (u32)f2bf(v0.z) | ((u32)f2bf(v0.w) << 16);
                u32 p2 = (u32)f2bf(v1.x) | ((u32)f2bf(v1.y) << 16);
                u32 p3 = (u32)f2bf(v1.z) | ((u32)f2bf(v1.w) << 16);
                int gp = g2 ^ ((row >> 1) & 3);
                *(uint4*)&As[row * 32 + gp * 8] = make_uint4(p0, p1, p2, p3);
            }
        }
        __syncthreads();
        bf16x8 af[4], bfr[4];
        #pragma unroll
        for (int i = 0; i < 4; i++) af[i] = *(const bf16x8*)&As[a_off[i]];
        #pragma unroll
        for (int i = 0; i < 4; i++) bfr[i] = *(const bf16x8*)&Bs[b_off[i]];
        #pragma unroll
        for (int mi = 0; mi < 4; mi++)
            #pragma unroll
            for (int ni = 0; ni < 4; ni++)
                acc[mi][ni] = __builtin_amdgcn_mfma_f32_16x16x32_bf16(
                    af[mi], bfr[ni], acc[mi][ni], 0, 0, 0);
        __syncthreads();
    }

    const int cn = n0 + wn + (lane & 15);
    const int rm = m0 + wm + (lane >> 4) * 4;
    #pragma unroll
    for (int mi = 0; mi < 4; mi++)
        #pragma unroll
        for (int ni = 0; ni < 4; ni++)
            #pragma unroll
            for (int r = 0; r < 4; r++)
                out[(size_t)(rm + mi * 16 + r) * 512 + cn + ni * 16] = acc[mi][ni][r];
}

// ---------------- K4: in-place row RMSNorm over 512 ----------------
__global__ __launch_bounds__(256) void k_norm(
    float* __restrict__ out, const float* __restrict__ nsc)
{
    __shared__ float part[2][2];
    const int t = threadIdx.x;
    const int r = t >> 7;
    const int cc = (t & 127) * 4;
    const size_t row = (size_t)blockIdx.x * 2 + r;
    float4 v = *(float4*)&out[row * 512 + cc];
    float ss = v.x * v.x + v.y * v.y + v.z * v.z + v.w * v.w;
    #pragma unroll
    for (int m = 1; m < 64; m <<= 1) ss += __shfl_xor(ss, m);
    if ((t & 63) == 0) part[r][(t >> 6) & 1] = ss;
    __syncthreads();
    float tot = part[r][0] + part[r][1];
    float rv = 1.0f / (sqrtf(tot * (1.0f / 512.0f)) + EPSF);
    const float4 s4 = *(const float4*)&nsc[cc];
    v.x *= rv * s4.x; v.y *= rv * s4.y; v.z *= rv * s4.z; v.w *= rv * s4.w;
    *(float4*)&out[row * 512 + cc] = v;
}

extern "C" void kernel_launch(void* const* d_in, const int* in_sizes, int n_in,
                              void* d_out, int out_size, void* d_ws, size_t ws_size,
                              hipStream_t stream)
{
    const float* x   = (const float*)d_in[0];
    const float* dw1 = (const float*)d_in[1];
    const float* pw1 = (const float*)d_in[2];
    const float* cn1 = (const float*)d_in[3];
    const float* dw3 = (const float*)d_in[4];
    const float* pw3 = (const float*)d_in[5];
    const float* cn3 = (const float*)d_in[6];
    const float* dw5 = (const float*)d_in[7];
    const float* pw5 = (const float*)d_in[8];
    const float* cn5 = (const float*)d_in[9];
    const float* dw7 = (const float*)d_in[10];
    const float* pw7 = (const float*)d_in[11];
    const float* cn7 = (const float*)d_in[12];
    const float* w1  = (const float*)d_in[13];
    const float* b1  = (const float*)d_in[14];
    const float* w2  = (const float*)d_in[15];
    const float* b2  = (const float*)d_in[16];
    const float* fw  = (const float*)d_in[17];
    const float* nsc = (const float*)d_in[18];
    const float* rw  = (const float*)d_in[19];

    // workspace: feats bf16 [65536][512] (64 MB) + packed W bf16 [512][768] (768 KB)
    u16* feats = (u16*)d_ws;
    u16* wbp   = (u16*)((char*)d_ws + (size_t)67108864);
    float* out = (float*)d_out;
    if (ws_size < (size_t)67895296) return;  // loud failure if scratch too small

    k_packw<<<dim3(512, 3), 256, 0, stream>>>(fw, rw, wbp);
    k_feats<<<dim3(128, 16), 256, 0, stream>>>(x, dw1, pw1, cn1, dw3, pw3, cn3,
                                               dw5, pw5, cn5, dw7, pw7, cn7, (u32*)feats);
    k_attn<<<dim3(4096), 256, 0, stream>>>(feats, w1, b1, w2, b2);
    k_final_mfma<<<dim3(512, 4), 256, 0, stream>>>(feats, x, wbp, out);
    k_norm<<<dim3(32768), 256, 0, stream>>>(out, nsc);
}

// Round 3
// 707.475 us; speedup vs baseline: 2.3997x; 1.5713x over previous
//
#include <hip/hip_runtime.h>
#include <hip/hip_bf16.h>
#include <math.h>

typedef unsigned int u32;
typedef unsigned short u16;

typedef __bf16 bf16_t;
typedef bf16_t bf16x8 __attribute__((ext_vector_type(8)));
typedef float f32x4 __attribute__((ext_vector_type(4)));

#define EPSF 1e-8f

__device__ __forceinline__ float bf2f(u16 h) {
    union { u32 u; float f; } v; v.u = ((u32)h) << 16; return v.f;
}
__device__ __forceinline__ u16 f2bf(float f) {
    union { float ff; u32 u; } v; v.ff = f;
    u32 u = v.u;
    return (u16)((u + 0x7fffu + ((u >> 16) & 1u)) >> 16);
}
__device__ __forceinline__ float gelu_exact(float v) {
    return 0.5f * v * (1.0f + erff(v * 0.70710678118654752440f));
}
__device__ __forceinline__ void gld_lds16(const void* g, void* l) {
    __builtin_amdgcn_global_load_lds(
        (const __attribute__((address_space(1))) unsigned int*)g,
        (__attribute__((address_space(3))) unsigned int*)l, 16, 0, 0);
}

// ---------------- K1: conv (fp32, registers) + MFMA pointwise + wave-local RMS + GELU ----------------
// Block: 32 L-positions, 256 threads. Conv writes H[4][32][256] bf16 (XOR-swizzled 8-ch groups)
// into 64 KB LDS. Then wave s GEMMs its scale: M=32 x N=128 x K=256, A from LDS, B from
// L2-cached packed bf16 weights. RMS is wave-local (in-reg + shfl_xor over 16 col-lanes).
template<int S>
__device__ __forceinline__ void conv_scale(
    const float* __restrict__ dw, const float* xc, u16* __restrict__ H, int c)
{
    const int K = 2 * S + 1;
    float d[K];
    #pragma unroll
    for (int j = 0; j < K; j++) d[j] = dw[c * K + j];
    const int chunk = c & ~31;
    const int q = (c >> 3) & 3;
    const int jj = c & 7;
    #pragma unroll
    for (int l = 0; l < 32; l++) {
        float a = 0.f;
        #pragma unroll
        for (int j = 0; j < K; j++) a += xc[l + 3 - S + j] * d[j];
        H[(S * 32 + l) * 256 + chunk + ((q ^ ((l >> 1) & 3)) << 3) + jj] = f2bf(a);
    }
}

__global__ __launch_bounds__(256) void k_feats(
    const float* __restrict__ x,
    const float* __restrict__ dw1, const float* __restrict__ dw3,
    const float* __restrict__ dw5, const float* __restrict__ dw7,
    const float* __restrict__ cn1, const float* __restrict__ cn3,
    const float* __restrict__ cn5, const float* __restrict__ cn7,
    const u16* __restrict__ pwb,
    u32* __restrict__ feats32)
{
    __shared__ __align__(16) u16 H[4 * 32 * 256];   // 64 KB; bounce-buffer overlay later
    const int t = threadIdx.x;
    const int lane = t & 63;
    const int wave = t >> 6;
    const int l0 = blockIdx.x * 32;
    const int b = blockIdx.y;
    const float* xb = x + (size_t)b * 4096 * 256;

    // x column (lane = channel) in registers, fp32
    float xc[38];
    #pragma unroll
    for (int r = 0; r < 38; r++) {
        int g = l0 - 3 + r;
        xc[r] = (g >= 0 && g < 4096) ? xb[(size_t)g * 256 + t] : 0.0f;
    }
    conv_scale<0>(dw1, xc, H, t);
    conv_scale<1>(dw3, xc, H, t);
    conv_scale<2>(dw5, xc, H, t);
    conv_scale<3>(dw7, xc, H, t);
    __syncthreads();

    // ---- per-wave GEMM: scale s = wave ----
    const int s = wave;
    const u16* wB = pwb + (size_t)s * 32768;   // [128][256] bf16
    const int col = lane & 15;
    const int q = lane >> 4;

    f32x4 acc[2][8];
    #pragma unroll
    for (int mt = 0; mt < 2; mt++)
        #pragma unroll
        for (int nt = 0; nt < 8; nt++) acc[mt][nt] = f32x4{0.f, 0.f, 0.f, 0.f};

    int a_off[2];
    #pragma unroll
    for (int mt = 0; mt < 2; mt++) {
        int m = mt * 16 + col;
        a_off[mt] = (s * 32 + m) * 256 + ((q ^ ((m >> 1) & 3)) << 3);
    }

    #pragma unroll 2
    for (int kt = 0; kt < 8; kt++) {
        bf16x8 af0 = *(const bf16x8*)&H[a_off[0] + kt * 32];
        bf16x8 af1 = *(const bf16x8*)&H[a_off[1] + kt * 32];
        #pragma unroll
        for (int nt = 0; nt < 8; nt++) {
            bf16x8 bfv = *(const bf16x8*)&wB[(nt * 16 + col) * 256 + kt * 32 + q * 8];
            acc[0][nt] = __builtin_amdgcn_mfma_f32_16x16x32_bf16(af0, bfv, acc[0][nt], 0, 0, 0);
            acc[1][nt] = __builtin_amdgcn_mfma_f32_16x16x32_bf16(af1, bfv, acc[1][nt], 0, 0, 0);
        }
    }

    // ---- wave-local RMS over the 128 channels of this scale ----
    float rinv_[2][4];
    #pragma unroll
    for (int mt = 0; mt < 2; mt++)
        #pragma unroll
        for (int r = 0; r < 4; r++) {
            float ss = 0.f;
            #pragma unroll
            for (int nt = 0; nt < 8; nt++) ss += acc[mt][nt][r] * acc[mt][nt][r];
            ss += __shfl_xor(ss, 1);
            ss += __shfl_xor(ss, 2);
            ss += __shfl_xor(ss, 4);
            ss += __shfl_xor(ss, 8);
            rinv_[mt][r] = 1.0f / (sqrtf(ss * (1.0f / 128.0f)) + EPSF);
        }

    const float* cn = (s == 0) ? cn1 : (s == 1) ? cn3 : (s == 2) ? cn5 : cn7;
    float cnv[8];
    #pragma unroll
    for (int nt = 0; nt < 8; nt++) cnv[nt] = cn[nt * 16 + col];

    __syncthreads();   // all GEMM reads of H complete before bounce overlay

    u16* bounce = H + s * 8192;   // [32][136] u16 region, overlays this wave's H slice
    #pragma unroll
    for (int mt = 0; mt < 2; mt++)
        #pragma unroll
        for (int nt = 0; nt < 8; nt++)
            #pragma unroll
            for (int r = 0; r < 4; r++) {
                int m = mt * 16 + q * 4 + r;
                float g = gelu_exact(acc[mt][nt][r] * rinv_[mt][r] * cnv[nt]);
                bounce[m * 136 + nt * 16 + col] = f2bf(g);
            }
    __syncthreads();

    // coalesced store: 64 lanes = 64 u32 (128 bf16 ch) per position
    const u32* b32 = (const u32*)bounce;
    size_t row0 = (size_t)b * 4096 + l0;
    #pragma unroll 4
    for (int m = 0; m < 32; m++)
        feats32[(row0 + m) * 256 + s * 64 + lane] = b32[m * 68 + lane];
}

// ---------------- K2: attention MLP + softmax + IN-PLACE feats scaling ----------------
__global__ __launch_bounds__(256) void k_attn(
    u16* __restrict__ feats,
    const float* __restrict__ w1, const float* __restrict__ b1,
    const float* __restrict__ w2, const float* __restrict__ b2)
{
    __shared__ float fsh[16 * 512];
    __shared__ float as1[16 * 132];
    __shared__ float att4[16][4];
    const int t = threadIdx.x;
    const size_t n0 = (size_t)blockIdx.x * 16;
    uint4* base = (uint4*)(feats + n0 * 512);
    uint4 v[4];
    #pragma unroll
    for (int i = 0; i < 4; i++) {
        v[i] = base[i * 256 + t];
        float* dst = &fsh[(i * 256 + t) * 8];
        dst[0] = bf2f((u16)(v[i].x & 0xffffu)); dst[1] = bf2f((u16)(v[i].x >> 16));
        dst[2] = bf2f((u16)(v[i].y & 0xffffu)); dst[3] = bf2f((u16)(v[i].y >> 16));
        dst[4] = bf2f((u16)(v[i].z & 0xffffu)); dst[5] = bf2f((u16)(v[i].z >> 16));
        dst[6] = bf2f((u16)(v[i].w & 0xffffu)); dst[7] = bf2f((u16)(v[i].w >> 16));
    }
    __syncthreads();
    {
        const int o = t & 127, half = t >> 7;
        const float* w1r = w1 + (size_t)o * 512;
        float acc[8];
        #pragma unroll
        for (int i = 0; i < 8; i++) acc[i] = 0.f;
        for (int c4 = 0; c4 < 512; c4 += 4) {
            float4 w = *(const float4*)(w1r + c4);
            #pragma unroll
            for (int i = 0; i < 8; i++) {
                const float4 f = *(const float4*)&fsh[(half * 8 + i) * 512 + c4];
                acc[i] += f.x * w.x + f.y * w.y + f.z * w.z + f.w * w.w;
            }
        }
        float bb = b1[o];
        #pragma unroll
        for (int i = 0; i < 8; i++)
            as1[(half * 8 + i) * 132 + o] = gelu_exact(acc[i] + bb);
    }
    __syncthreads();
    {
        const int p = t >> 4, part = t & 15;
        float a2[4] = {0.f, 0.f, 0.f, 0.f};
        #pragma unroll
        for (int j = 0; j < 8; j++) {
            int o = part * 8 + j;
            float av = as1[p * 132 + o];
            #pragma unroll
            for (int s = 0; s < 4; s++) a2[s] += av * w2[s * 128 + o];
        }
        #pragma unroll
        for (int m = 1; m < 16; m <<= 1) {
            #pragma unroll
            for (int s = 0; s < 4; s++) a2[s] += __shfl_xor(a2[s], m);
        }
        if (part == 0) {
            float v0 = a2[0] + b2[0], v1 = a2[1] + b2[1], v2 = a2[2] + b2[2], v3 = a2[3] + b2[3];
            float mx = fmaxf(fmaxf(v0, v1), fmaxf(v2, v3));
            float e0 = expf(v0 - mx), e1 = expf(v1 - mx), e2 = expf(v2 - mx), e3 = expf(v3 - mx);
            float inv = 1.0f / (e0 + e1 + e2 + e3);
            att4[p][0] = e0 * inv; att4[p][1] = e1 * inv; att4[p][2] = e2 * inv; att4[p][3] = e3 * inv;
        }
    }
    __syncthreads();
    #pragma unroll
    for (int i = 0; i < 4; i++) {
        int idx = i * 256 + t;
        int row = idx >> 6;
        int sc = (idx & 63) >> 4;
        float a = att4[row][sc];
        uint4 w = v[i];
        u32 r0 = (u32)f2bf(bf2f((u16)(w.x & 0xffffu)) * a) | ((u32)f2bf(bf2f((u16)(w.x >> 16)) * a) << 16);
        u32 r1 = (u32)f2bf(bf2f((u16)(w.y & 0xffffu)) * a) | ((u32)f2bf(bf2f((u16)(w.y >> 16)) * a) << 16);
        u32 r2 = (u32)f2bf(bf2f((u16)(w.z & 0xffffu)) * a) | ((u32)f2bf(bf2f((u16)(w.z >> 16)) * a) << 16);
        u32 r3 = (u32)f2bf(bf2f((u16)(w.w & 0xffffu)) * a) | ((u32)f2bf(bf2f((u16)(w.w >> 16)) * a) << 16);
        base[idx] = make_uint4(r0, r1, r2, r3);
    }
}

// ---------------- K2b: pack final_w || res_w into bf16 [512][768] ----------------
__global__ __launch_bounds__(256) void k_packw(
    const float* __restrict__ fw, const float* __restrict__ rw, u16* __restrict__ wb)
{
    const int n = blockIdx.x;
    const int k = blockIdx.y * 256 + threadIdx.x;
    float v = (k < 512) ? fw[(size_t)n * 512 + k] : rw[(size_t)n * 256 + (k - 512)];
    wb[(size_t)n * 768 + k] = f2bf(v);
}

// ---------------- K2c: pack pw1/3/5/7 into bf16 [4][128][256] ----------------
__global__ __launch_bounds__(256) void k_packpw(
    const float* __restrict__ pw1, const float* __restrict__ pw3,
    const float* __restrict__ pw5, const float* __restrict__ pw7,
    u16* __restrict__ pwb)
{
    const int s = blockIdx.y;
    const float* pw = (s == 0) ? pw1 : (s == 1) ? pw3 : (s == 2) ? pw5 : pw7;
    const int i = blockIdx.x * 256 + threadIdx.x;
    pwb[(size_t)s * 32768 + i] = f2bf(pw[i]);
}

// ---------------- K3: MFMA GEMM — out[65536,512] = A[65536,768] * W[512,768]^T ----------------
__global__ __launch_bounds__(256) void k_final_mfma(
    const u16* __restrict__ feats, const float* __restrict__ x,
    const u16* __restrict__ wb, float* __restrict__ out)
{
    __shared__ __align__(16) u16 As[128 * 32];
    __shared__ __align__(16) u16 Bs[128 * 32];
    const int t = threadIdx.x;
    const int lane = t & 63;
    const int wave = t >> 6;
    const int m0 = blockIdx.x * 128;
    const int n0 = blockIdx.y * 128;

    const int srow_b = wave * 32 + (lane >> 2);
    const int sgp = lane & 3;

    f32x4 acc[4][4];
    #pragma unroll
    for (int i = 0; i < 4; i++)
        #pragma unroll
        for (int j = 0; j < 4; j++) acc[i][j] = f32x4{0.f, 0.f, 0.f, 0.f};

    const int wm = (wave & 1) * 64;
    const int wn = (wave >> 1) * 64;
    int a_off[4], b_off[4];
    #pragma unroll
    for (int i = 0; i < 4; i++) {
        int ra = wm + i * 16 + (lane & 15);
        a_off[i] = ra * 32 + (((lane >> 4) ^ ((ra >> 1) & 3)) * 8);
        int rb = wn + i * 16 + (lane & 15);
        b_off[i] = rb * 32 + (((lane >> 4) ^ ((rb >> 1) & 3)) * 8);
    }

    for (int kt = 0; kt < 24; ++kt) {
        const int k0 = kt * 32;
        #pragma unroll
        for (int j = 0; j < 2; j++) {
            int r = srow_b + j * 16;
            int g = sgp ^ ((r >> 1) & 3);
            gld_lds16(wb + (size_t)(n0 + r) * 768 + k0 + g * 8,
                      &Bs[wave * 1024 + j * 512]);
        }
        if (kt < 16) {
            #pragma unroll
            for (int j = 0; j < 2; j++) {
                int r = srow_b + j * 16;
                int g = sgp ^ ((r >> 1) & 3);
                gld_lds16(feats + (size_t)(m0 + r) * 512 + k0 + g * 8,
                          &As[wave * 1024 + j * 512]);
            }
        } else {
            const int kx0 = (kt - 16) * 32;
            const int row = t >> 1;
            #pragma unroll
            for (int h = 0; h < 2; h++) {
                int g2 = (t & 1) * 2 + h;
                const float4* xp = (const float4*)(x + (size_t)(m0 + row) * 256 + kx0 + g2 * 8);
                float4 v0 = xp[0], v1 = xp[1];
                u32 p0 = (u32)f2bf(v0.x) | ((u32)f2bf(v0.y) << 16);
                u32 p1 = (u32)f2bf(v0.z) | ((u32)f2bf(v0.w) << 16);
                u32 p2 = (u32)f2bf(v1.x) | ((u32)f2bf(v1.y) << 16);
                u32 p3 = (u32)f2bf(v1.z) | ((u32)f2bf(v1.w) << 16);
                int gp = g2 ^ ((row >> 1) & 3);
                *(uint4*)&As[row * 32 + gp * 8] = make_uint4(p0, p1, p2, p3);
            }
        }
        __syncthreads();
        bf16x8 af[4], bfr[4];
        #pragma unroll
        for (int i = 0; i < 4; i++) af[i] = *(const bf16x8*)&As[a_off[i]];
        #pragma unroll
        for (int i = 0; i < 4; i++) bfr[i] = *(const bf16x8*)&Bs[b_off[i]];
        #pragma unroll
        for (int mi = 0; mi < 4; mi++)
            #pragma unroll
            for (int ni = 0; ni < 4; ni++)
                acc[mi][ni] = __builtin_amdgcn_mfma_f32_16x16x32_bf16(
                    af[mi], bfr[ni], acc[mi][ni], 0, 0, 0);
        __syncthreads();
    }

    const int cn = n0 + wn + (lane & 15);
    const int rm = m0 + wm + (lane >> 4) * 4;
    #pragma unroll
    for (int mi = 0; mi < 4; mi++)
        #pragma unroll
        for (int ni = 0; ni < 4; ni++)
            #pragma unroll
            for (int r = 0; r < 4; r++)
                out[(size_t)(rm + mi * 16 + r) * 512 + cn + ni * 16] = acc[mi][ni][r];
}

// ---------------- K4: in-place row RMSNorm over 512 ----------------
__global__ __launch_bounds__(256) void k_norm(
    float* __restrict__ out, const float* __restrict__ nsc)
{
    __shared__ float part[2][2];
    const int t = threadIdx.x;
    const int r = t >> 7;
    const int cc = (t & 127) * 4;
    const size_t row = (size_t)blockIdx.x * 2 + r;
    float4 v = *(float4*)&out[row * 512 + cc];
    float ss = v.x * v.x + v.y * v.y + v.z * v.z + v.w * v.w;
    #pragma unroll
    for (int m = 1; m < 64; m <<= 1) ss += __shfl_xor(ss, m);
    if ((t & 63) == 0) part[r][(t >> 6) & 1] = ss;
    __syncthreads();
    float tot = part[r][0] + part[r][1];
    float rv = 1.0f / (sqrtf(tot * (1.0f / 512.0f)) + EPSF);
    const float4 s4 = *(const float4*)&nsc[cc];
    v.x *= rv * s4.x; v.y *= rv * s4.y; v.z *= rv * s4.z; v.w *= rv * s4.w;
    *(float4*)&out[row * 512 + cc] = v;
}

extern "C" void kernel_launch(void* const* d_in, const int* in_sizes, int n_in,
                              void* d_out, int out_size, void* d_ws, size_t ws_size,
                              hipStream_t stream)
{
    const float* x   = (const float*)d_in[0];
    const float* dw1 = (const float*)d_in[1];
    const float* pw1 = (const float*)d_in[2];
    const float* cn1 = (const float*)d_in[3];
    const float* dw3 = (const float*)d_in[4];
    const float* pw3 = (const float*)d_in[5];
    const float* cn3 = (const float*)d_in[6];
    const float* dw5 = (const float*)d_in[7];
    const float* pw5 = (const float*)d_in[8];
    const float* cn5 = (const float*)d_in[9];
    const float* dw7 = (const float*)d_in[10];
    const float* pw7 = (const float*)d_in[11];
    const float* cn7 = (const float*)d_in[12];
    const float* w1  = (const float*)d_in[13];
    const float* b1  = (const float*)d_in[14];
    const float* w2  = (const float*)d_in[15];
    const float* b2  = (const float*)d_in[16];
    const float* fw  = (const float*)d_in[17];
    const float* nsc = (const float*)d_in[18];
    const float* rw  = (const float*)d_in[19];

    // ws: feats bf16 [65536][512] @0 (64MB) | wb bf16 [512][768] @64MB (768KB) | pwb bf16 [4][128][256] (256KB)
    u16* feats = (u16*)d_ws;
    u16* wbp   = (u16*)((char*)d_ws + (size_t)67108864);
    u16* pwb   = (u16*)((char*)d_ws + (size_t)67895296);
    float* out = (float*)d_out;
    if (ws_size < (size_t)68157440) return;  // loud failure if scratch too small

    k_packw<<<dim3(512, 3), 256, 0, stream>>>(fw, rw, wbp);
    k_packpw<<<dim3(128, 4), 256, 0, stream>>>(pw1, pw3, pw5, pw7, pwb);
    k_feats<<<dim3(128, 16), 256, 0, stream>>>(x, dw1, dw3, dw5, dw7,
                                               cn1, cn3, cn5, cn7, pwb, (u32*)feats);
    k_attn<<<dim3(4096), 256, 0, stream>>>(feats, w1, b1, w2, b2);
    k_final_mfma<<<dim3(512, 4), 256, 0, stream>>>(feats, x, wbp, out);
    k_norm<<<dim3(32768), 256, 0, stream>>>(out, nsc);
}